// Round 5
// baseline (379.971 us; speedup 1.0000x reference)
//
#include <hip/hip_runtime.h>

// Sparse 3D conv, gather formulation, R10: spatial feature compaction +
// XCD-aware block swizzle, so each XCD's gather working set (map slab +
// feature slab) is L2-resident.
//
// Theory (R3 counters): gather is L3-latency bound — feat rows were indexed
// by random voxel id, ~430 MB of 64 B cache-line traffic / 58 us = 7.4 TB/s
// hitting Infinity Cache. Fix: rank head voxels per (b,z)-plane (atomicAdd
// counters), store rows plane-major -> per-XCD z-slab (~3.4 MB) fits 4 MB L2.
//
// prep:       map[B*96^3] = -1, zero plane counters, pack W -> bf16 B-frags.
// build_map:  map[site] = vi via atomicExch; duplicate chain via nxt[vi].
// merge_feat: chain heads get fp32-summed, bf16-packed rows at spatially
//             ranked slot; map[site] overwritten with TAG+idx (TAG=1<<30
//             keeps rank space disjoint from voxel-id space -> no races).
// gather:     R9 pipeline (map 2 ahead, feat 1 ahead), swizzled block id.

#define DGRID 96
#define DOUT 48
#define CIN 32
#define COUT 64
#define NOFF 27
#define NSITE (2 * DGRID * DGRID * DGRID)     // 1,769,472 sites (B=2)
#define WPACK_ELEMS (NOFF * 4 * 64 * 8)       // 55,296 bf16
#define NTILE (2 * DOUT * DOUT * DOUT / 16)   // 13,824 tiles of 16 outputs
#define TPW 2                                 // tiles per wave
#define NWAVE (NTILE / TPW)                   // 6,912 waves -> 1,728 blocks
#define NBLK (NWAVE / 4)
#define NXCD 8
#define NPLANE (2 * DGRID)                    // 192 (b,z) planes
#define PCAP 1344                             // rows per plane (mean 1042 + 9.4 sigma)
#define RTAG (1 << 30)                        // rank tag in map[]

typedef __attribute__((ext_vector_type(8))) short bf16x8;
typedef __attribute__((ext_vector_type(4))) float f32x4;

static __device__ __forceinline__ unsigned short f2bf_rne(float x) {
    unsigned u = __float_as_uint(x);
    u += 0x7fffu + ((u >> 16) & 1u);
    return (unsigned short)(u >> 16);
}

// Pack two fp32 -> bf16x2, round-half-up (same 2^-9 error bound as RNE).
static __device__ __forceinline__ unsigned pk_bf16(float lo, float hi) {
    unsigned a = __float_as_uint(lo) + 0x8000u;
    unsigned b = __float_as_uint(hi) + 0x8000u;
    return __builtin_amdgcn_perm(b, a, 0x07060302u);
}

// ws: int map[NSITE] | int nxt[N] | int cnt[NPLANE] | bf16 featbf[NPLANE*PCAP*CIN] | bf16 Wpack

__global__ __launch_bounds__(256) void prep_kernel(
    const float* __restrict__ W, int* __restrict__ map,
    int* __restrict__ cnt, unsigned short* __restrict__ Wpack)
{
    const int tid = blockIdx.x * 256 + threadIdx.x;
    if (tid < NSITE / 4) {
        ((int4*)map)[tid] = make_int4(-1, -1, -1, -1);
        return;
    }
    const int w = tid - NSITE / 4;
    if (w < WPACK_ELEMS) {
        // Wpack[((o*4+f)*64+l)*8+j] = bf16(W[o][k][cout]),
        // k = (l>>4)*8 + j, cout = f*16 + (l&15).  (validated R4-R6)
        const int j = w & 7, l = (w >> 3) & 63, f = (w >> 9) & 3, o = w >> 11;
        const int k    = ((l >> 4) << 3) + j;
        const int cout = (f << 4) + (l & 15);
        Wpack[w] = f2bf_rne(W[(o * CIN + k) * COUT + cout]);
        return;
    }
    const int w2 = w - WPACK_ELEMS;
    if (w2 < NPLANE / 4)
        ((int4*)cnt)[w2] = make_int4(0, 0, 0, 0);
}

__global__ __launch_bounds__(256) void build_map_kernel(
    const int* __restrict__ coors, int* __restrict__ map,
    int* __restrict__ nxt, int N)
{
    const int vi = blockIdx.x * 256 + threadIdx.x;
    if (vi >= N) return;
    const int b = coors[vi * 4 + 0];
    const int z = coors[vi * 4 + 1];
    const int y = coors[vi * 4 + 2];
    const int x = coors[vi * 4 + 3];
    const int site = ((b * DGRID + z) * DGRID + y) * DGRID + x;
    nxt[vi] = atomicExch(&map[site], vi);   // chain head swap (handles dups)
}

// 8 threads per voxel (part = 4 channels each). Chain heads sum duplicate
// rows in fp32, take a per-(b,z)-plane rank, store the bf16 row at the
// plane-major slot, and retag map[site] with TAG+idx. TAG keeps rank values
// disjoint from voxel ids, so other voxels' head-checks (map!=vi) stay
// correct regardless of write timing.
__global__ __launch_bounds__(256) void merge_feat_kernel(
    const float* __restrict__ feat, const int* __restrict__ coors,
    int* __restrict__ map, const int* __restrict__ nxt,
    int* __restrict__ cnt, unsigned short* __restrict__ featbf, int N)
{
    const int tid = blockIdx.x * 256 + threadIdx.x;
    const int vi = tid >> 3, part = tid & 7;
    if (vi >= N) return;
    const int b = coors[vi * 4 + 0];
    const int z = coors[vi * 4 + 1];
    const int y = coors[vi * 4 + 2];
    const int x = coors[vi * 4 + 3];
    const int site = ((b * DGRID + z) * DGRID + y) * DGRID + x;
    if (map[site] != vi) return;          // not a chain head
    float4 s = *(const float4*)(feat + (size_t)vi * CIN + part * 4);
    int v2 = nxt[vi];
    while (v2 >= 0) {                     // ~3% of voxels; usually 0 iters
        const float4 u = *(const float4*)(feat + (size_t)v2 * CIN + part * 4);
        s.x += u.x; s.y += u.y; s.z += u.z; s.w += u.w;
        v2 = nxt[v2];
    }
    // One rank per voxel (part 0), broadcast to the other 7 lanes of the
    // 8-lane group (same wave, active together).
    const int plane = b * DGRID + z;
    int rank = 0;
    if (part == 0) rank = atomicAdd(&cnt[plane], 1);
    const int lane = threadIdx.x & 63;
    rank = __shfl(rank, lane & ~7);
    const int idx = plane * PCAP + rank;

    uint2 p;
    p.x = pk_bf16(s.x, s.y);
    p.y = pk_bf16(s.z, s.w);
    *(uint2*)(featbf + (size_t)idx * CIN + part * 4) = p;
    if (part == 0) map[site] = RTAG + idx;
}

__global__ __launch_bounds__(256) void spconv_gather_kernel(
    const unsigned short* __restrict__ featbf,  // [NPLANE*PCAP, CIN] bf16
    const int*            __restrict__ map,     // [NSITE] TAG+idx or -1
    const unsigned short* __restrict__ Wpack,   // bf16 B-frag layout
    float*                __restrict__ out)     // [B*DOUT^3, COUT]
{
    const int lane  = threadIdx.x & 63;
    const int col   = lane & 15;      // output row within tile / C col
    const int khalf = lane >> 4;      // k-chunk for A-frag, row group for C
    // XCD-aware bijective swizzle: XCD k owns contiguous tile range ->
    // its map slab (~1.0 MB) + feat slab (~2.4 MB) are L2-resident.
    const int bid  = blockIdx.x;
    const int sbid = (bid & (NXCD - 1)) * (NBLK / NXCD) + (bid >> 3);
    const int wid  = sbid * 4 + (threadIdx.x >> 6);   // 0..NWAVE-1

    // Fold the rank tag into the base pointer (zero per-load VALU cost).
    const unsigned short* fb = featbf - (size_t)RTAG * CIN;

    // Decode this wave's tiles (wave-uniform -> SGPRs). Tile t=1 is the
    // same (z,y,x) in batch 1 (tau+NWAVE flips b only).
    int tb[TPW], tzo[TPW], tyo[TPW], txb[TPW];
#pragma unroll
    for (int t = 0; t < TPW; ++t) {
        const int tau = wid + t * NWAVE;
        const int x16 = tau % 3;
        const int r2  = tau / 3;
        tyo[t] = r2 % DOUT;
        const int r3 = r2 / DOUT;
        tzo[t] = r3 % DOUT;
        tb[t]  = r3 / DOUT;
        txb[t] = x16 << 4;
    }

    f32x4 acc[TPW][4];
#pragma unroll
    for (int t = 0; t < TPW; ++t)
#pragma unroll
        for (int q = 0; q < 4; ++q)
            acc[t][q] = (f32x4){0.f, 0.f, 0.f, 0.f};

    // Issue the map-row loads for kernel offset `off` (independent gathers).
    auto ldmap = [&](int off, int (&m)[TPW]) {
        const int kx = off % 3, ky = (off / 3) % 3, kz = off / 9;
#pragma unroll
        for (int t = 0; t < TPW; ++t) {
            const int zi = 2 * tzo[t] - 1 + kz;
            const int yi = 2 * tyo[t] - 1 + ky;
            int v = -1;
            if ((unsigned)zi < DGRID && (unsigned)yi < DGRID) {
                const int xi = 2 * (txb[t] + col) - 1 + kx;
                if ((unsigned)xi < DGRID)
                    v = map[((tb[t] * DGRID + zi) * DGRID + yi) * DGRID + xi];
            }
            m[t] = v;
        }
    };

    // Feature-row gathers + active mask for one offset's map values.
    auto ldfeat = [&](const int (&m)[TPW], bf16x8 (&af)[TPW], bool (&act)[TPW]) {
#pragma unroll
        for (int t = 0; t < TPW; ++t) {
            act[t] = __ballot(m[t] >= 0) != 0ull;
            af[t] = (bf16x8)0;
            if (m[t] >= 0)
                af[t] = *(const bf16x8*)(fb + (size_t)m[t] * CIN + (khalf << 3));
        }
    };

    // Pipeline prologue: map for off=0 and off=1 in flight, feat for off=0.
    int m0[TPW], m_nxt[TPW];
    ldmap(0, m0);
    ldmap(1, m_nxt);
    bf16x8 af_cur[TPW];
    bool   act_cur[TPW];
    ldfeat(m0, af_cur, act_cur);

    for (int off = 0; off < NOFF; ++off) {
        // B-frags for this offset (L1-hot after first wave).
        const bf16x8* wp = (const bf16x8*)Wpack + off * 256 + lane;
        const bf16x8 b0 = wp[0];
        const bf16x8 b1 = wp[64];
        const bf16x8 b2 = wp[128];
        const bf16x8 b3 = wp[192];

        // Map loads for off+2 go in flight now.
        int m_nn[TPW] = { -1, -1 };
        if (off + 2 < NOFF) ldmap(off + 2, m_nn);

        // Feat gathers for off+1 go in flight now (map row arrived ~1 iter ago).
        bf16x8 af_nxt[TPW];
        bool   act_nxt[TPW];
#pragma unroll
        for (int t = 0; t < TPW; ++t) { af_nxt[t] = (bf16x8)0; act_nxt[t] = false; }
        if (off + 1 < NOFF) ldfeat(m_nxt, af_nxt, act_nxt);

        // MFMA consumes feat rows issued a full iteration ago.
#pragma unroll
        for (int t = 0; t < TPW; ++t) {
            if (!act_cur[t]) continue;   // ~15% of rows entirely empty
            acc[t][0] = __builtin_amdgcn_mfma_f32_16x16x32_bf16(af_cur[t], b0, acc[t][0], 0, 0, 0);
            acc[t][1] = __builtin_amdgcn_mfma_f32_16x16x32_bf16(af_cur[t], b1, acc[t][1], 0, 0, 0);
            acc[t][2] = __builtin_amdgcn_mfma_f32_16x16x32_bf16(af_cur[t], b2, acc[t][2], 0, 0, 0);
            acc[t][3] = __builtin_amdgcn_mfma_f32_16x16x32_bf16(af_cur[t], b3, acc[t][3], 0, 0, 0);
        }

        // Rotate pipeline state (static indices only -> stays in registers).
#pragma unroll
        for (int t = 0; t < TPW; ++t) {
            m_nxt[t]   = m_nn[t];
            af_cur[t]  = af_nxt[t];
            act_cur[t] = act_nxt[t];
        }
    }

    // Epilogue: plain coalesced stores; covers every output element once
    // (also provides the zeros -> no output memset anywhere).
    // C layout: col = lane&15, row = khalf*4 + r (HW-verified mapping).
#pragma unroll
    for (int t = 0; t < TPW; ++t) {
        const int tau = wid + t * NWAVE;
        float* ob = out + (size_t)tau * 16 * COUT;
#pragma unroll
        for (int r = 0; r < 4; ++r) {
            float* op = ob + ((khalf << 2) + r) * COUT + col;
            op[0]  = acc[t][0][r];
            op[16] = acc[t][1][r];
            op[32] = acc[t][2][r];
            op[48] = acc[t][3][r];
        }
    }
}

extern "C" void kernel_launch(void* const* d_in, const int* in_sizes, int n_in,
                              void* d_out, int out_size, void* d_ws, size_t ws_size,
                              hipStream_t stream) {
    const float* feat  = (const float*)d_in[0];
    const int*   coors = (const int*)d_in[1];
    const float* W     = (const float*)d_in[3];
    float*       out   = (float*)d_out;

    const int N = in_sizes[0] / CIN;  // 200000

    char* ws = (char*)d_ws;
    int* map = (int*)ws;                                        // 7,077,888 B
    int* nxt = (int*)(ws + (size_t)NSITE * 4);                  //   800,000 B
    const size_t cnt_off = (size_t)NSITE * 4 + (((size_t)N * 4 + 63) & ~(size_t)63);
    int* cnt = (int*)(ws + cnt_off);                            //       768 B
    const size_t featbf_off = cnt_off + ((NPLANE * 4 + 63) & ~63);
    unsigned short* featbf = (unsigned short*)(ws + featbf_off);        // 16.5 MB
    const size_t wpack_off = featbf_off + (((size_t)NPLANE * PCAP * CIN * 2 + 15) & ~(size_t)15);
    unsigned short* Wpack = (unsigned short*)(ws + wpack_off);          // 110,592 B
    // total ws use ~24.5 MB

    const int prep_threads = NSITE / 4 + WPACK_ELEMS + NPLANE / 4;
    prep_kernel<<<(prep_threads + 255) / 256, 256, 0, stream>>>(W, map, cnt, Wpack);

    build_map_kernel<<<(N + 255) / 256, 256, 0, stream>>>(coors, map, nxt, N);

    merge_feat_kernel<<<(N * 8 + 255) / 256, 256, 0, stream>>>(
        feat, coors, map, nxt, cnt, featbf, N);

    spconv_gather_kernel<<<NWAVE / 4, 256, 0, stream>>>(featbf, map, Wpack, out);
}

// Round 6
// 160.650 us; speedup vs baseline: 2.3652x; 2.3652x over previous
//
#include <hip/hip_runtime.h>

// Sparse 3D conv, gather formulation, R11: spatial compaction WITHOUT atomics.
// R10's per-plane atomicAdd ranking ping-ponged 12 cache lines across 8 XCDs
// (merge_feat 10us -> 236us). Replace with a deterministic per-plane site
// scan: 1 block per (b,z)-plane, LDS prefix sum, site-sequential ranks.
//
// prep:       map[NSITE] = -1, head[NPLANE*PCAP] = -1, pack W -> bf16 B-frags.
// build_map:  map[site] = vi via atomicExch; duplicate chain via nxt[vi].
// rank:       block p scans its 9216 sites (36/thread, in regs), LDS scan,
//             map[site] = RTAG + plane*PCAP + rank, head[idx] = vi. 0 atomics.
// merge:      8 threads per compact slot: vi = head[idx] (skip -1), fp32-sum
//             dup chain, write bf16 row coalesced at slot idx.
// gather:     R9/R10 pipeline (map 2 ahead, feat 1 ahead), XCD block swizzle,
//             feat rows now site-ordered per plane -> L2-friendly.

#define DGRID 96
#define DOUT 48
#define CIN 32
#define COUT 64
#define NOFF 27
#define NSITE (2 * DGRID * DGRID * DGRID)     // 1,769,472 sites (B=2)
#define WPACK_ELEMS (NOFF * 4 * 64 * 8)       // 55,296 bf16
#define NTILE (2 * DOUT * DOUT * DOUT / 16)   // 13,824 tiles of 16 outputs
#define TPW 2                                 // tiles per wave
#define NWAVE (NTILE / TPW)                   // 6,912 waves -> 1,728 blocks
#define NBLK (NWAVE / 4)
#define NXCD 8
#define NPLANE (2 * DGRID)                    // 192 (b,z) planes
#define PSITES (DGRID * DGRID)                // 9216 sites per plane
#define SPT (PSITES / 256)                    // 36 sites per rank-thread
#define PCAP 1344                             // slots/plane (mean ~985 + 12 sigma)
#define NSLOT (NPLANE * PCAP)                 // 258,048 compact slots
#define RTAG (1 << 30)                        // rank tag in map[]

typedef __attribute__((ext_vector_type(8))) short bf16x8;
typedef __attribute__((ext_vector_type(4))) float f32x4;

static __device__ __forceinline__ unsigned short f2bf_rne(float x) {
    unsigned u = __float_as_uint(x);
    u += 0x7fffu + ((u >> 16) & 1u);
    return (unsigned short)(u >> 16);
}

// Pack two fp32 -> bf16x2, round-half-up (same 2^-9 error bound as RNE).
static __device__ __forceinline__ unsigned pk_bf16(float lo, float hi) {
    unsigned a = __float_as_uint(lo) + 0x8000u;
    unsigned b = __float_as_uint(hi) + 0x8000u;
    return __builtin_amdgcn_perm(b, a, 0x07060302u);
}

// ws: int map[NSITE] | int nxt[N] | int head[NSLOT] | bf16 featbf[NSLOT*CIN] | bf16 Wpack

__global__ __launch_bounds__(256) void prep_kernel(
    const float* __restrict__ W, int* __restrict__ map,
    int* __restrict__ head, unsigned short* __restrict__ Wpack)
{
    const int tid = blockIdx.x * 256 + threadIdx.x;
    if (tid < NSITE / 4) {
        ((int4*)map)[tid] = make_int4(-1, -1, -1, -1);
        return;
    }
    const int w = tid - NSITE / 4;
    if (w < NSLOT / 4) {
        ((int4*)head)[w] = make_int4(-1, -1, -1, -1);
        return;
    }
    const int w2 = w - NSLOT / 4;
    if (w2 < WPACK_ELEMS) {
        // Wpack[((o*4+f)*64+l)*8+j] = bf16(W[o][k][cout]),
        // k = (l>>4)*8 + j, cout = f*16 + (l&15).  (validated R4-R6)
        const int j = w2 & 7, l = (w2 >> 3) & 63, f = (w2 >> 9) & 3, o = w2 >> 11;
        const int k    = ((l >> 4) << 3) + j;
        const int cout = (f << 4) + (l & 15);
        Wpack[w2] = f2bf_rne(W[(o * CIN + k) * COUT + cout]);
    }
}

__global__ __launch_bounds__(256) void build_map_kernel(
    const int* __restrict__ coors, int* __restrict__ map,
    int* __restrict__ nxt, int N)
{
    const int vi = blockIdx.x * 256 + threadIdx.x;
    if (vi >= N) return;
    const int b = coors[vi * 4 + 0];
    const int z = coors[vi * 4 + 1];
    const int y = coors[vi * 4 + 2];
    const int x = coors[vi * 4 + 3];
    const int site = ((b * DGRID + z) * DGRID + y) * DGRID + x;
    nxt[vi] = atomicExch(&map[site], vi);   // chain head swap (handles dups)
}

// One block per (b,z)-plane. Deterministic site-sequential ranking, no
// atomics: load 36 map entries/thread into registers, LDS prefix-sum the
// per-thread head counts, rewrite occupied sites to RTAG+idx, record
// head[idx] = vi. Runs after build_map, before merge.
__global__ __launch_bounds__(256) void rank_kernel(
    int* __restrict__ map, int* __restrict__ head)
{
    const int p = blockIdx.x;               // plane id
    const int i = threadIdx.x;
    const int base = p * PSITES;

    int v[SPT];
    int cnt = 0;
#pragma unroll
    for (int k = 0; k < SPT; ++k) {
        v[k] = map[base + i + k * 256];     // coalesced, 36 loads in flight
        cnt += (v[k] >= 0) ? 1 : 0;
    }

    __shared__ int sc[256];
    sc[i] = cnt;
    __syncthreads();
#pragma unroll
    for (int d = 1; d < 256; d <<= 1) {     // Hillis-Steele inclusive scan
        int t = (i >= d) ? sc[i - d] : 0;
        __syncthreads();
        sc[i] += t;
        __syncthreads();
    }
    int idx = p * PCAP + sc[i] - cnt;       // exclusive prefix -> first slot

#pragma unroll
    for (int k = 0; k < SPT; ++k) {
        if (v[k] >= 0) {
            map[base + i + k * 256] = RTAG + idx;
            head[idx] = v[k];
            ++idx;
        }
    }
}

// 8 threads per compact slot (part = 4 channels each). Empty slots skipped.
// fp32-sum the duplicate chain, write the bf16 row coalesced at slot idx.
__global__ __launch_bounds__(256) void merge_feat_kernel(
    const float* __restrict__ feat, const int* __restrict__ head,
    const int* __restrict__ nxt, unsigned short* __restrict__ featbf)
{
    const int tid = blockIdx.x * 256 + threadIdx.x;
    const int slot = tid >> 3, part = tid & 7;
    if (slot >= NSLOT) return;
    const int vi = head[slot];
    if (vi < 0) return;                   // unused slot (~27% of PCAP padding)
    float4 s = *(const float4*)(feat + (size_t)vi * CIN + part * 4);
    int v2 = nxt[vi];
    while (v2 >= 0) {                     // ~5% of sites; usually 0 iters
        const float4 u = *(const float4*)(feat + (size_t)v2 * CIN + part * 4);
        s.x += u.x; s.y += u.y; s.z += u.z; s.w += u.w;
        v2 = nxt[v2];
    }
    uint2 pkd;
    pkd.x = pk_bf16(s.x, s.y);
    pkd.y = pk_bf16(s.z, s.w);
    *(uint2*)(featbf + (size_t)slot * CIN + part * 4) = pkd;
}

__global__ __launch_bounds__(256) void spconv_gather_kernel(
    const unsigned short* __restrict__ featbf,  // [NSLOT, CIN] bf16, site-ordered
    const int*            __restrict__ map,     // [NSITE] RTAG+idx or -1
    const unsigned short* __restrict__ Wpack,   // bf16 B-frag layout
    float*                __restrict__ out)     // [B*DOUT^3, COUT]
{
    const int lane  = threadIdx.x & 63;
    const int col   = lane & 15;      // output row within tile / C col
    const int khalf = lane >> 4;      // k-chunk for A-frag, row group for C
    // XCD-aware bijective swizzle: XCD k owns a contiguous z-major tile range
    // -> its map slab (~1.0 MB) + feat slab (~2.4 MB) are L2-resident.
    const int bid  = blockIdx.x;
    const int sbid = (bid & (NXCD - 1)) * (NBLK / NXCD) + (bid >> 3);
    const int wid  = sbid * 4 + (threadIdx.x >> 6);   // 0..NWAVE-1

    // Fold the rank tag into the base pointer (zero per-load VALU cost).
    const unsigned short* fb = featbf - (size_t)RTAG * CIN;

    // Decode this wave's tiles (wave-uniform -> SGPRs).
    int tb[TPW], tzo[TPW], tyo[TPW], txb[TPW];
#pragma unroll
    for (int t = 0; t < TPW; ++t) {
        const int tau = wid + t * NWAVE;
        const int x16 = tau % 3;
        const int r2  = tau / 3;
        tyo[t] = r2 % DOUT;
        const int r3 = r2 / DOUT;
        tzo[t] = r3 % DOUT;
        tb[t]  = r3 / DOUT;
        txb[t] = x16 << 4;
    }

    f32x4 acc[TPW][4];
#pragma unroll
    for (int t = 0; t < TPW; ++t)
#pragma unroll
        for (int q = 0; q < 4; ++q)
            acc[t][q] = (f32x4){0.f, 0.f, 0.f, 0.f};

    // Issue the map-row loads for kernel offset `off` (independent gathers).
    auto ldmap = [&](int off, int (&m)[TPW]) {
        const int kx = off % 3, ky = (off / 3) % 3, kz = off / 9;
#pragma unroll
        for (int t = 0; t < TPW; ++t) {
            const int zi = 2 * tzo[t] - 1 + kz;
            const int yi = 2 * tyo[t] - 1 + ky;
            int v = -1;
            if ((unsigned)zi < DGRID && (unsigned)yi < DGRID) {
                const int xi = 2 * (txb[t] + col) - 1 + kx;
                if ((unsigned)xi < DGRID)
                    v = map[((tb[t] * DGRID + zi) * DGRID + yi) * DGRID + xi];
            }
            m[t] = v;
        }
    };

    // Feature-row gathers + active mask for one offset's map values.
    auto ldfeat = [&](const int (&m)[TPW], bf16x8 (&af)[TPW], bool (&act)[TPW]) {
#pragma unroll
        for (int t = 0; t < TPW; ++t) {
            act[t] = __ballot(m[t] >= 0) != 0ull;
            af[t] = (bf16x8)0;
            if (m[t] >= 0)
                af[t] = *(const bf16x8*)(fb + (size_t)m[t] * CIN + (khalf << 3));
        }
    };

    // Pipeline prologue: map for off=0 and off=1 in flight, feat for off=0.
    int m0[TPW], m_nxt[TPW];
    ldmap(0, m0);
    ldmap(1, m_nxt);
    bf16x8 af_cur[TPW];
    bool   act_cur[TPW];
    ldfeat(m0, af_cur, act_cur);

    for (int off = 0; off < NOFF; ++off) {
        // B-frags for this offset (L1-hot after first wave).
        const bf16x8* wp = (const bf16x8*)Wpack + off * 256 + lane;
        const bf16x8 b0 = wp[0];
        const bf16x8 b1 = wp[64];
        const bf16x8 b2 = wp[128];
        const bf16x8 b3 = wp[192];

        // Map loads for off+2 go in flight now.
        int m_nn[TPW] = { -1, -1 };
        if (off + 2 < NOFF) ldmap(off + 2, m_nn);

        // Feat gathers for off+1 go in flight now (map row arrived ~1 iter ago).
        bf16x8 af_nxt[TPW];
        bool   act_nxt[TPW];
#pragma unroll
        for (int t = 0; t < TPW; ++t) { af_nxt[t] = (bf16x8)0; act_nxt[t] = false; }
        if (off + 1 < NOFF) ldfeat(m_nxt, af_nxt, act_nxt);

        // MFMA consumes feat rows issued a full iteration ago.
#pragma unroll
        for (int t = 0; t < TPW; ++t) {
            if (!act_cur[t]) continue;   // ~15% of rows entirely empty
            acc[t][0] = __builtin_amdgcn_mfma_f32_16x16x32_bf16(af_cur[t], b0, acc[t][0], 0, 0, 0);
            acc[t][1] = __builtin_amdgcn_mfma_f32_16x16x32_bf16(af_cur[t], b1, acc[t][1], 0, 0, 0);
            acc[t][2] = __builtin_amdgcn_mfma_f32_16x16x32_bf16(af_cur[t], b2, acc[t][2], 0, 0, 0);
            acc[t][3] = __builtin_amdgcn_mfma_f32_16x16x32_bf16(af_cur[t], b3, acc[t][3], 0, 0, 0);
        }

        // Rotate pipeline state (static indices only -> stays in registers).
#pragma unroll
        for (int t = 0; t < TPW; ++t) {
            m_nxt[t]   = m_nn[t];
            af_cur[t]  = af_nxt[t];
            act_cur[t] = act_nxt[t];
        }
    }

    // Epilogue: plain coalesced stores; covers every output element once
    // (also provides the zeros -> no output memset anywhere).
    // C layout: col = lane&15, row = khalf*4 + r (HW-verified mapping).
#pragma unroll
    for (int t = 0; t < TPW; ++t) {
        const int tau = wid + t * NWAVE;
        float* ob = out + (size_t)tau * 16 * COUT;
#pragma unroll
        for (int r = 0; r < 4; ++r) {
            float* op = ob + ((khalf << 2) + r) * COUT + col;
            op[0]  = acc[t][0][r];
            op[16] = acc[t][1][r];
            op[32] = acc[t][2][r];
            op[48] = acc[t][3][r];
        }
    }
}

extern "C" void kernel_launch(void* const* d_in, const int* in_sizes, int n_in,
                              void* d_out, int out_size, void* d_ws, size_t ws_size,
                              hipStream_t stream) {
    const float* feat  = (const float*)d_in[0];
    const int*   coors = (const int*)d_in[1];
    const float* W     = (const float*)d_in[3];
    float*       out   = (float*)d_out;

    const int N = in_sizes[0] / CIN;  // 200000

    char* ws = (char*)d_ws;
    int* map = (int*)ws;                                        // 7,077,888 B
    int* nxt = (int*)(ws + (size_t)NSITE * 4);                  //   800,000 B
    const size_t head_off = (size_t)NSITE * 4 + (((size_t)N * 4 + 63) & ~(size_t)63);
    int* head = (int*)(ws + head_off);                          // 1,032,192 B
    const size_t featbf_off = head_off + (size_t)NSLOT * 4;
    unsigned short* featbf = (unsigned short*)(ws + featbf_off);        // 16.5 MB
    const size_t wpack_off = featbf_off + (size_t)NSLOT * CIN * 2;
    unsigned short* Wpack = (unsigned short*)(ws + wpack_off);          // 110,592 B
    // total ws use ~25.5 MB

    const int prep_threads = NSITE / 4 + NSLOT / 4 + WPACK_ELEMS;
    prep_kernel<<<(prep_threads + 255) / 256, 256, 0, stream>>>(W, map, head, Wpack);

    build_map_kernel<<<(N + 255) / 256, 256, 0, stream>>>(coors, map, nxt, N);

    rank_kernel<<<NPLANE, 256, 0, stream>>>(map, head);

    merge_feat_kernel<<<(NSLOT * 8 + 255) / 256, 256, 0, stream>>>(
        feat, head, nxt, featbf);

    spconv_gather_kernel<<<NWAVE / 4, 256, 0, stream>>>(featbf, map, Wpack, out);
}

// Round 9
// 155.998 us; speedup vs baseline: 2.4357x; 1.0298x over previous
//
#include <hip/hip_runtime.h>
#include <hip/hip_cooperative_groups.h>

namespace cg = cooperative_groups;

// Sparse 3D conv, R13. Two changes vs R12:
//  (a) DEADLOCK GUARD: R12 hung twice — theory: fused kernel compiled to
//      >64 VGPR -> 4 blocks/CU -> 1024 co-resident < 1728 grid -> grid.sync
//      deadlock (HIP's coop validation didn't reject). Now we query
//      hipOccupancyMaxActiveBlocksPerMultiprocessor and require
//      blocks/CU * 256 >= NBLK before cooperative launch; else proven
//      4-kernel path. No hang possible on either path.
//  (b) Strength-reduced gather map addressing (both paths): per-tile
//      mapbase hoisted; per-offset index = mapbase + (kz*9216+ky*96+kx)
//      (wave-uniform SALU); validity = precomputed sign flags. ~25 -> ~6
//      VALU/iter, also trims VGPR pressure (helps (a)'s condition).
//
// Fused phases (grid = 1728 x 256, 3 grid.syncs):
//   P1 map=-1 + Wpack | P2 build_map | P3 merge_feat | P4 gather.

#define DGRID 96
#define DOUT 48
#define CIN 32
#define COUT 64
#define NOFF 27
#define NSITE (2 * DGRID * DGRID * DGRID)     // 1,769,472 sites (B=2)
#define WPACK_ELEMS (NOFF * 4 * 64 * 8)       // 55,296 bf16
#define NTILE (2 * DOUT * DOUT * DOUT / 16)   // 13,824 tiles of 16 outputs
#define TPW 2                                 // tiles per wave
#define NWAVE (NTILE / TPW)                   // 6,912 waves
#define NBLK (NWAVE / 4)                      // 1,728 blocks (= NSITE/4/256)
#define NCU 256                               // MI355X CUs

typedef __attribute__((ext_vector_type(8))) short bf16x8;
typedef __attribute__((ext_vector_type(4))) float f32x4;

static __device__ __forceinline__ unsigned short f2bf_rne(float x) {
    unsigned u = __float_as_uint(x);
    u += 0x7fffu + ((u >> 16) & 1u);
    return (unsigned short)(u >> 16);
}

// Pack two fp32 -> bf16x2, round-half-up (same 2^-9 error bound as RNE).
static __device__ __forceinline__ unsigned pk_bf16(float lo, float hi) {
    unsigned a = __float_as_uint(lo) + 0x8000u;
    unsigned b = __float_as_uint(hi) + 0x8000u;
    return __builtin_amdgcn_perm(b, a, 0x07060302u);
}

// ---------------------------------------------------------------------------
// Shared phase bodies.
// ---------------------------------------------------------------------------

static __device__ __forceinline__ void wpack_one(
    const float* __restrict__ W, unsigned short* __restrict__ Wpack, int w)
{
    // Wpack[((o*4+f)*64+l)*8+j] = bf16(W[o][k][cout]),
    // k = (l>>4)*8 + j, cout = f*16 + (l&15).  (validated R4-R6)
    const int j = w & 7, l = (w >> 3) & 63, f = (w >> 9) & 3, o = w >> 11;
    const int k    = ((l >> 4) << 3) + j;
    const int cout = (f << 4) + (l & 15);
    Wpack[w] = f2bf_rne(W[(o * CIN + k) * COUT + cout]);
}

static __device__ __forceinline__ void build_one(
    const int* __restrict__ coors, int* __restrict__ map,
    int* __restrict__ nxt, int vi)
{
    const int b = coors[vi * 4 + 0];
    const int z = coors[vi * 4 + 1];
    const int y = coors[vi * 4 + 2];
    const int x = coors[vi * 4 + 3];
    const int site = ((b * DGRID + z) * DGRID + y) * DGRID + x;
    nxt[vi] = atomicExch(&map[site], vi);   // chain head swap (handles dups)
}

// 8 threads per voxel (part = 4 channels each). Chain heads sum duplicate
// rows in fp32 and store a 64 B bf16 row; non-heads are never read.
static __device__ __forceinline__ void merge_one(
    const float* __restrict__ feat, const int* __restrict__ coors,
    const int* __restrict__ map, const int* __restrict__ nxt,
    unsigned short* __restrict__ featbf, int tid)
{
    const int vi = tid >> 3, part = tid & 7;
    const int b = coors[vi * 4 + 0];
    const int z = coors[vi * 4 + 1];
    const int y = coors[vi * 4 + 2];
    const int x = coors[vi * 4 + 3];
    const int site = ((b * DGRID + z) * DGRID + y) * DGRID + x;
    if (map[site] != vi) return;          // not a chain head
    float4 s = *(const float4*)(feat + (size_t)vi * CIN + part * 4);
    int v2 = nxt[vi];
    while (v2 >= 0) {                     // ~3% of voxels; usually 0 iters
        const float4 u = *(const float4*)(feat + (size_t)v2 * CIN + part * 4);
        s.x += u.x; s.y += u.y; s.z += u.z; s.w += u.w;
        v2 = nxt[v2];
    }
    uint2 p;
    p.x = pk_bf16(s.x, s.y);
    p.y = pk_bf16(s.z, s.w);
    *(uint2*)(featbf + (size_t)vi * CIN + part * 4) = p;
}

// Gather phase body. wid in [0, NWAVE); lane = 64-lane id.
static __device__ __forceinline__ void gather_body(
    const unsigned short* __restrict__ featbf,
    const int*            __restrict__ map,
    const unsigned short* __restrict__ Wpack,
    float*                __restrict__ out,
    int wid, int lane)
{
    const int col   = lane & 15;      // output row within tile / C col
    const int khalf = lane >> 4;      // k-chunk for A-frag, row group for C

    // Decode this wave's tiles (wave-uniform -> SGPRs).
    int tb[TPW], tzo[TPW], tyo[TPW], txb[TPW];
#pragma unroll
    for (int t = 0; t < TPW; ++t) {
        const int tau = wid + t * NWAVE;
        const int x16 = tau % 3;
        const int r2  = tau / 3;
        tyo[t] = r2 % DOUT;
        const int r3 = r2 / DOUT;
        tzo[t] = r3 % DOUT;
        tb[t]  = r3 / DOUT;
        txb[t] = x16 << 4;
    }

    // Hoisted map addressing (R13): per-tile base computed once.
    //   idx(off) = mapbase + kz*9216 + ky*96 + kx   (delta is wave-uniform)
    //   validity: zi = 2tzo-1+kz in [0,96) <=> (kz>0 || tzo>0); y likewise;
    //             xi = 2(txb+col)-1+kx   <=> (kx>0 || txb+col>0).
    //   Upper bounds never trip (max index 2*47-1+2 = 95).
    int  mapbase[TPW];
    bool zpos[TPW], ypos[TPW], xpos[TPW];
#pragma unroll
    for (int t = 0; t < TPW; ++t) {
        const int zi0 = 2 * tzo[t] - 1;
        const int yi0 = 2 * tyo[t] - 1;
        const int xi0 = 2 * (txb[t] + col) - 1;
        mapbase[t] = ((tb[t] * DGRID + zi0) * DGRID + yi0) * DGRID + xi0;
        zpos[t] = tzo[t] > 0;
        ypos[t] = tyo[t] > 0;
        xpos[t] = (txb[t] + col) > 0;
    }

    f32x4 acc[TPW][4];
#pragma unroll
    for (int t = 0; t < TPW; ++t)
#pragma unroll
        for (int q = 0; q < 4; ++q)
            acc[t][q] = (f32x4){0.f, 0.f, 0.f, 0.f};

    // Issue the map-row loads for kernel offset `off` (independent gathers).
    auto ldmap = [&](int off, int (&m)[TPW]) {
        const int kx = off % 3, ky = (off / 3) % 3, kz = off / 9;
        const int doff = (kz * DGRID + ky) * DGRID + kx;   // scalar
#pragma unroll
        for (int t = 0; t < TPW; ++t) {
            const bool ok = (kz > 0 || zpos[t]) && (ky > 0 || ypos[t]) &&
                            (kx > 0 || xpos[t]);
            m[t] = ok ? map[mapbase[t] + doff] : -1;
        }
    };

    // Feature-row gathers + active mask for one offset's map values.
    auto ldfeat = [&](const int (&m)[TPW], bf16x8 (&af)[TPW], bool (&act)[TPW]) {
#pragma unroll
        for (int t = 0; t < TPW; ++t) {
            act[t] = __ballot(m[t] >= 0) != 0ull;
            af[t] = (bf16x8)0;
            if (m[t] >= 0)
                af[t] = *(const bf16x8*)(featbf + (size_t)m[t] * CIN + (khalf << 3));
        }
    };

    // Pipeline prologue: map for off=0 and off=1 in flight, feat for off=0.
    int m0[TPW], m_nxt[TPW];
    ldmap(0, m0);
    ldmap(1, m_nxt);
    bf16x8 af_cur[TPW];
    bool   act_cur[TPW];
    ldfeat(m0, af_cur, act_cur);

    for (int off = 0; off < NOFF; ++off) {
        // B-frags for this offset (L1-hot after first wave).
        const bf16x8* wp = (const bf16x8*)Wpack + off * 256 + lane;
        const bf16x8 b0 = wp[0];
        const bf16x8 b1 = wp[64];
        const bf16x8 b2 = wp[128];
        const bf16x8 b3 = wp[192];

        // Map loads for off+2 go in flight now.
        int m_nn[TPW] = { -1, -1 };
        if (off + 2 < NOFF) ldmap(off + 2, m_nn);

        // Feat gathers for off+1 go in flight now (map row arrived ~1 iter ago).
        bf16x8 af_nxt[TPW];
        bool   act_nxt[TPW];
#pragma unroll
        for (int t = 0; t < TPW; ++t) { af_nxt[t] = (bf16x8)0; act_nxt[t] = false; }
        if (off + 1 < NOFF) ldfeat(m_nxt, af_nxt, act_nxt);

        // MFMA consumes feat rows issued a full iteration ago; the waitcnt
        // here leaves this iteration's map+feat loads in flight.
#pragma unroll
        for (int t = 0; t < TPW; ++t) {
            if (!act_cur[t]) continue;   // ~15% of rows entirely empty
            acc[t][0] = __builtin_amdgcn_mfma_f32_16x16x32_bf16(af_cur[t], b0, acc[t][0], 0, 0, 0);
            acc[t][1] = __builtin_amdgcn_mfma_f32_16x16x32_bf16(af_cur[t], b1, acc[t][1], 0, 0, 0);
            acc[t][2] = __builtin_amdgcn_mfma_f32_16x16x32_bf16(af_cur[t], b2, acc[t][2], 0, 0, 0);
            acc[t][3] = __builtin_amdgcn_mfma_f32_16x16x32_bf16(af_cur[t], b3, acc[t][3], 0, 0, 0);
        }

        // Rotate pipeline state (static indices only -> stays in registers).
#pragma unroll
        for (int t = 0; t < TPW; ++t) {
            m_nxt[t]   = m_nn[t];
            af_cur[t]  = af_nxt[t];
            act_cur[t] = act_nxt[t];
        }
    }

    // Epilogue: plain coalesced stores; covers every output element once
    // (also provides the zeros -> no output memset anywhere).
    // C layout: col = lane&15, row = khalf*4 + r (HW-verified mapping).
#pragma unroll
    for (int t = 0; t < TPW; ++t) {
        const int tau = wid + t * NWAVE;
        float* ob = out + (size_t)tau * 16 * COUT;
#pragma unroll
        for (int r = 0; r < 4; ++r) {
            float* op = ob + ((khalf << 2) + r) * COUT + col;
            op[0]  = acc[t][0][r];
            op[16] = acc[t][1][r];
            op[32] = acc[t][2][r];
            op[48] = acc[t][3][r];
        }
    }
}

// ---------------------------------------------------------------------------
// Fused cooperative kernel (launched ONLY if the occupancy guard passes).
// ---------------------------------------------------------------------------

__global__ __launch_bounds__(256) void spconv_fused_kernel(
    const float* __restrict__ feat, const int* __restrict__ coors,
    const float* __restrict__ W, float* __restrict__ out,
    int* __restrict__ map, int* __restrict__ nxt,
    unsigned short* __restrict__ featbf, unsigned short* __restrict__ Wpack,
    int N)
{
    cg::grid_group grid = cg::this_grid();
    const int gtid = blockIdx.x * 256 + threadIdx.x;   // 0 .. 442,367

    // P1: map init (exactly one int4 per thread: NSITE/4 == NBLK*256) + Wpack.
    ((int4*)map)[gtid] = make_int4(-1, -1, -1, -1);
    if (gtid < WPACK_ELEMS) wpack_one(W, Wpack, gtid);
    grid.sync();

    // P2: build_map (N = 200k < 442k: single pass).
    if (gtid < N) build_one(coors, map, nxt, gtid);
    grid.sync();

    // P3: merge_feat, grid-stride over N*8 work items (~4 passes).
    for (int tid = gtid; tid < N * 8; tid += NBLK * 256)
        merge_one(feat, coors, map, nxt, featbf, tid);
    grid.sync();

    // P4: gather. wid = gtid>>6 covers [0, NWAVE) exactly.
    gather_body(featbf, map, Wpack, out, gtid >> 6, threadIdx.x & 63);
}

// ---------------------------------------------------------------------------
// 4-kernel path (R9-proven structure + R13 addressing).
// ---------------------------------------------------------------------------

__global__ __launch_bounds__(256) void prep_kernel(
    const float* __restrict__ W, int* __restrict__ map,
    unsigned short* __restrict__ Wpack)
{
    const int tid = blockIdx.x * 256 + threadIdx.x;
    if (tid < NSITE / 4) {
        ((int4*)map)[tid] = make_int4(-1, -1, -1, -1);
        return;
    }
    const int w = tid - NSITE / 4;
    if (w < WPACK_ELEMS) wpack_one(W, Wpack, w);
}

__global__ __launch_bounds__(256) void build_map_kernel(
    const int* __restrict__ coors, int* __restrict__ map,
    int* __restrict__ nxt, int N)
{
    const int vi = blockIdx.x * 256 + threadIdx.x;
    if (vi >= N) return;
    build_one(coors, map, nxt, vi);
}

__global__ __launch_bounds__(256) void merge_feat_kernel(
    const float* __restrict__ feat, const int* __restrict__ coors,
    const int* __restrict__ map, const int* __restrict__ nxt,
    unsigned short* __restrict__ featbf, int N)
{
    const int tid = blockIdx.x * 256 + threadIdx.x;
    if (tid >= N * 8) return;
    merge_one(feat, coors, map, nxt, featbf, tid);
}

__global__ __launch_bounds__(256) void spconv_gather_kernel(
    const unsigned short* __restrict__ featbf,
    const int*            __restrict__ map,
    const unsigned short* __restrict__ Wpack,
    float*                __restrict__ out)
{
    const int wid = blockIdx.x * 4 + (threadIdx.x >> 6);
    gather_body(featbf, map, Wpack, out, wid, threadIdx.x & 63);
}

// ---------------------------------------------------------------------------

extern "C" void kernel_launch(void* const* d_in, const int* in_sizes, int n_in,
                              void* d_out, int out_size, void* d_ws, size_t ws_size,
                              hipStream_t stream) {
    const float* feat  = (const float*)d_in[0];
    const int*   coors = (const int*)d_in[1];
    const float* W     = (const float*)d_in[3];
    float*       out   = (float*)d_out;

    const int N = in_sizes[0] / CIN;  // 200000

    char* ws = (char*)d_ws;
    int* map = (int*)ws;                                        // 7,077,888 B
    int* nxt = (int*)(ws + (size_t)NSITE * 4);                  //   800,000 B
    const size_t featbf_off = (size_t)NSITE * 4 + (((size_t)N * 4 + 63) & ~(size_t)63);
    unsigned short* featbf = (unsigned short*)(ws + featbf_off);        // 12.8 MB
    const size_t wpack_off = featbf_off + (((size_t)N * CIN * 2 + 15) & ~(size_t)15);
    unsigned short* Wpack = (unsigned short*)(ws + wpack_off);          // 110,592 B
    // total ws use ~20.8 MB

    // Co-residency guard (host-side query, graph-capture safe, cached).
    // R12 lesson: HIP let an over-capacity cooperative grid launch and
    // grid.sync() deadlocked. Require blocks/CU * NCU >= NBLK explicitly.
    static int coop_ok = -1;
    if (coop_ok < 0) {
        int nb = 0;
        hipError_t qe = hipOccupancyMaxActiveBlocksPerMultiprocessor(
            &nb, spconv_fused_kernel, 256, 0);
        coop_ok = (qe == hipSuccess && nb * NCU >= NBLK) ? 1 : 0;
    }

    bool launched = false;
    if (coop_ok == 1) {
        void* kargs[] = {
            (void*)&feat, (void*)&coors, (void*)&W, (void*)&out,
            (void*)&map, (void*)&nxt, (void*)&featbf, (void*)&Wpack, (void*)&N
        };
        hipError_t e = hipLaunchCooperativeKernel(
            (const void*)spconv_fused_kernel, dim3(NBLK), dim3(256), kargs, 0, stream);
        launched = (e == hipSuccess);
    }

    if (!launched) {
        // Proven 4-kernel pipeline (R9 structure, R13 gather addressing).
        const int prep_blocks = (NSITE / 4 + WPACK_ELEMS + 255) / 256;
        prep_kernel<<<prep_blocks, 256, 0, stream>>>(W, map, Wpack);
        build_map_kernel<<<(N + 255) / 256, 256, 0, stream>>>(coors, map, nxt, N);
        merge_feat_kernel<<<(N * 8 + 255) / 256, 256, 0, stream>>>(
            feat, coors, map, nxt, featbf, N);
        spconv_gather_kernel<<<NWAVE / 4, 256, 0, stream>>>(featbf, map, Wpack, out);
    }
}

// Round 10
// 154.417 us; speedup vs baseline: 2.4607x; 1.0102x over previous
//
#include <hip/hip_runtime.h>

// Sparse 3D conv, R14: FULL UNROLL of the gather's 27-offset loop.
//
// R13 evidence: gather stuck at ~58 us with VALUBusy halved (33->18%) and
// every pipe <40% utilized -> ~5100 cycles exposed latency per wave-iter.
// Cause theory: runtime loop forces af_cur=af_nxt register rotation; the
// v_mov from the just-issued feat-load dest makes the compiler s_waitcnt on
// THIS iteration's loads at the bottom of the SAME iteration — the prefetch
// never survives the backedge. Full unroll (NOFF=27 compile-time) turns
// rotation into renaming; loads genuinely stay in flight one iteration.
//
// Fusion: REMOVED permanently (R9/R13: fused kernel >64 VGPR -> only 4
// blocks/CU -> 1728-block grid.sync deadlock; guard always routed away).
//
// prep:       map[B*96^3] = -1, pack W -> bf16 MFMA B-frags.
// build_map:  map[site] = vi via atomicExch; duplicate chain via nxt[vi].
// merge_feat: chain heads get fp32-summed, bf16-packed feature rows (64 B).
// gather:     wave owns 2 tiles of 16 outputs; map 2 ahead, feat 1 ahead,
//             hoisted mapbase + sign-flag validity (R13); 8 MFMA/offset into
//             persistent C regs; plain coalesced stores (no memset).

#define DGRID 96
#define DOUT 48
#define CIN 32
#define COUT 64
#define NOFF 27
#define NSITE (2 * DGRID * DGRID * DGRID)     // 1,769,472 sites (B=2)
#define WPACK_ELEMS (NOFF * 4 * 64 * 8)       // 55,296 bf16
#define NTILE (2 * DOUT * DOUT * DOUT / 16)   // 13,824 tiles of 16 outputs
#define TPW 2                                 // tiles per wave
#define NWAVE (NTILE / TPW)                   // 6,912 waves -> 1,728 blocks

typedef __attribute__((ext_vector_type(8))) short bf16x8;
typedef __attribute__((ext_vector_type(4))) float f32x4;

static __device__ __forceinline__ unsigned short f2bf_rne(float x) {
    unsigned u = __float_as_uint(x);
    u += 0x7fffu + ((u >> 16) & 1u);
    return (unsigned short)(u >> 16);
}

// Pack two fp32 -> bf16x2, round-half-up (same 2^-9 error bound as RNE).
static __device__ __forceinline__ unsigned pk_bf16(float lo, float hi) {
    unsigned a = __float_as_uint(lo) + 0x8000u;
    unsigned b = __float_as_uint(hi) + 0x8000u;
    return __builtin_amdgcn_perm(b, a, 0x07060302u);
}

// ws layout: int map[NSITE] | int nxt[N] (64B-pad) | bf16 featbf[N*CIN] | bf16 Wpack

__global__ __launch_bounds__(256) void prep_kernel(
    const float* __restrict__ W, int* __restrict__ map,
    unsigned short* __restrict__ Wpack)
{
    const int tid = blockIdx.x * 256 + threadIdx.x;
    if (tid < NSITE / 4) {
        ((int4*)map)[tid] = make_int4(-1, -1, -1, -1);
        return;
    }
    const int w = tid - NSITE / 4;
    if (w < WPACK_ELEMS) {
        // Wpack[((o*4+f)*64+l)*8+j] = bf16(W[o][k][cout]),
        // k = (l>>4)*8 + j, cout = f*16 + (l&15).  (validated R4-R6)
        const int j = w & 7, l = (w >> 3) & 63, f = (w >> 9) & 3, o = w >> 11;
        const int k    = ((l >> 4) << 3) + j;
        const int cout = (f << 4) + (l & 15);
        Wpack[w] = f2bf_rne(W[(o * CIN + k) * COUT + cout]);
    }
}

__global__ __launch_bounds__(256) void build_map_kernel(
    const int* __restrict__ coors, int* __restrict__ map,
    int* __restrict__ nxt, int N)
{
    const int vi = blockIdx.x * 256 + threadIdx.x;
    if (vi >= N) return;
    const int b = coors[vi * 4 + 0];
    const int z = coors[vi * 4 + 1];
    const int y = coors[vi * 4 + 2];
    const int x = coors[vi * 4 + 3];
    const int site = ((b * DGRID + z) * DGRID + y) * DGRID + x;
    nxt[vi] = atomicExch(&map[site], vi);   // chain head swap (handles dups)
}

// 8 threads per voxel (part = 4 channels each). Chain heads sum duplicate
// rows in fp32 and store a 64 B bf16 row; non-heads are never read.
__global__ __launch_bounds__(256) void merge_feat_kernel(
    const float* __restrict__ feat, const int* __restrict__ coors,
    const int* __restrict__ map, const int* __restrict__ nxt,
    unsigned short* __restrict__ featbf, int N)
{
    const int tid = blockIdx.x * 256 + threadIdx.x;
    const int vi = tid >> 3, part = tid & 7;
    if (vi >= N) return;
    const int b = coors[vi * 4 + 0];
    const int z = coors[vi * 4 + 1];
    const int y = coors[vi * 4 + 2];
    const int x = coors[vi * 4 + 3];
    const int site = ((b * DGRID + z) * DGRID + y) * DGRID + x;
    if (map[site] != vi) return;          // not a chain head
    float4 s = *(const float4*)(feat + (size_t)vi * CIN + part * 4);
    int v2 = nxt[vi];
    while (v2 >= 0) {                     // ~3% of voxels; usually 0 iters
        const float4 u = *(const float4*)(feat + (size_t)v2 * CIN + part * 4);
        s.x += u.x; s.y += u.y; s.z += u.z; s.w += u.w;
        v2 = nxt[v2];
    }
    uint2 p;
    p.x = pk_bf16(s.x, s.y);
    p.y = pk_bf16(s.z, s.w);
    *(uint2*)(featbf + (size_t)vi * CIN + part * 4) = p;
}

__global__ __launch_bounds__(256) void spconv_gather_kernel(
    const unsigned short* __restrict__ featbf,  // [N, CIN] bf16, chain-merged
    const int*            __restrict__ map,     // [NSITE] head voxel or -1
    const unsigned short* __restrict__ Wpack,   // bf16 B-frag layout
    float*                __restrict__ out)     // [B*DOUT^3, COUT]
{
    const int lane  = threadIdx.x & 63;
    const int col   = lane & 15;      // output row within tile / C col
    const int khalf = lane >> 4;      // k-chunk for A-frag, row group for C
    const int wid   = blockIdx.x * 4 + (threadIdx.x >> 6);   // 0..NWAVE-1

    // Decode this wave's tiles (wave-uniform -> SGPRs).
    int tb[TPW], tzo[TPW], tyo[TPW], txb[TPW];
#pragma unroll
    for (int t = 0; t < TPW; ++t) {
        const int tau = wid + t * NWAVE;
        const int x16 = tau % 3;
        const int r2  = tau / 3;
        tyo[t] = r2 % DOUT;
        const int r3 = r2 / DOUT;
        tzo[t] = r3 % DOUT;
        tb[t]  = r3 / DOUT;
        txb[t] = x16 << 4;
    }

    // Hoisted map addressing (R13): per-tile base computed once.
    //   idx(off) = mapbase + kz*9216 + ky*96 + kx   (delta is compile-time
    //   after full unroll). validity via sign flags; upper bounds never trip.
    int  mapbase[TPW];
    bool zpos[TPW], ypos[TPW], xpos[TPW];
#pragma unroll
    for (int t = 0; t < TPW; ++t) {
        const int zi0 = 2 * tzo[t] - 1;
        const int yi0 = 2 * tyo[t] - 1;
        const int xi0 = 2 * (txb[t] + col) - 1;
        mapbase[t] = ((tb[t] * DGRID + zi0) * DGRID + yi0) * DGRID + xi0;
        zpos[t] = tzo[t] > 0;
        ypos[t] = tyo[t] > 0;
        xpos[t] = (txb[t] + col) > 0;
    }

    f32x4 acc[TPW][4];
#pragma unroll
    for (int t = 0; t < TPW; ++t)
#pragma unroll
        for (int q = 0; q < 4; ++q)
            acc[t][q] = (f32x4){0.f, 0.f, 0.f, 0.f};

    auto ldmap = [&](int off, int (&m)[TPW]) {
        const int kx = off % 3, ky = (off / 3) % 3, kz = off / 9;
        const int doff = (kz * DGRID + ky) * DGRID + kx;   // const after unroll
#pragma unroll
        for (int t = 0; t < TPW; ++t) {
            const bool ok = (kz > 0 || zpos[t]) && (ky > 0 || ypos[t]) &&
                            (kx > 0 || xpos[t]);
            m[t] = ok ? map[mapbase[t] + doff] : -1;
        }
    };

    auto ldfeat = [&](const int (&m)[TPW], bf16x8 (&af)[TPW], bool (&act)[TPW]) {
#pragma unroll
        for (int t = 0; t < TPW; ++t) {
            act[t] = __ballot(m[t] >= 0) != 0ull;
            af[t] = (bf16x8)0;
            if (m[t] >= 0)
                af[t] = *(const bf16x8*)(featbf + (size_t)m[t] * CIN + (khalf << 3));
        }
    };

    // Pipeline prologue: map for off=0 and off=1 in flight, feat for off=0.
    int m0[TPW], m_nxt[TPW];
    ldmap(0, m0);
    ldmap(1, m_nxt);
    bf16x8 af_cur[TPW];
    bool   act_cur[TPW];
    ldfeat(m0, af_cur, act_cur);

    // FULL UNROLL (R14): rotation becomes register renaming; the feat loads
    // issued in iteration `off` are first WAITED on in iteration off+1's
    // MFMA, not at this iteration's backedge.
#pragma unroll
    for (int off = 0; off < NOFF; ++off) {
        // B-frags for this offset (L1-hot after first wave; const offsets).
        const bf16x8* wp = (const bf16x8*)Wpack + off * 256 + lane;
        const bf16x8 b0 = wp[0];
        const bf16x8 b1 = wp[64];
        const bf16x8 b2 = wp[128];
        const bf16x8 b3 = wp[192];

        // Map loads for off+2 go in flight now.
        int m_nn[TPW] = { -1, -1 };
        if (off + 2 < NOFF) ldmap(off + 2, m_nn);

        // Feat gathers for off+1 go in flight now.
        bf16x8 af_nxt[TPW];
        bool   act_nxt[TPW];
#pragma unroll
        for (int t = 0; t < TPW; ++t) { af_nxt[t] = (bf16x8)0; act_nxt[t] = false; }
        if (off + 1 < NOFF) ldfeat(m_nxt, af_nxt, act_nxt);

        // MFMA consumes feat rows issued a full iteration ago.
#pragma unroll
        for (int t = 0; t < TPW; ++t) {
            if (!act_cur[t]) continue;   // ~15% of rows entirely empty
            acc[t][0] = __builtin_amdgcn_mfma_f32_16x16x32_bf16(af_cur[t], b0, acc[t][0], 0, 0, 0);
            acc[t][1] = __builtin_amdgcn_mfma_f32_16x16x32_bf16(af_cur[t], b1, acc[t][1], 0, 0, 0);
            acc[t][2] = __builtin_amdgcn_mfma_f32_16x16x32_bf16(af_cur[t], b2, acc[t][2], 0, 0, 0);
            acc[t][3] = __builtin_amdgcn_mfma_f32_16x16x32_bf16(af_cur[t], b3, acc[t][3], 0, 0, 0);
        }

        // Rotate (renamed away by the unroll; static indices only).
#pragma unroll
        for (int t = 0; t < TPW; ++t) {
            m_nxt[t]   = m_nn[t];
            af_cur[t]  = af_nxt[t];
            act_cur[t] = act_nxt[t];
        }
    }

    // Epilogue: plain coalesced stores; covers every output element once
    // (also provides the zeros -> no output memset anywhere).
    // C layout: col = lane&15, row = khalf*4 + r (HW-verified mapping).
#pragma unroll
    for (int t = 0; t < TPW; ++t) {
        const int tau = wid + t * NWAVE;
        float* ob = out + (size_t)tau * 16 * COUT;
#pragma unroll
        for (int r = 0; r < 4; ++r) {
            float* op = ob + ((khalf << 2) + r) * COUT + col;
            op[0]  = acc[t][0][r];
            op[16] = acc[t][1][r];
            op[32] = acc[t][2][r];
            op[48] = acc[t][3][r];
        }
    }
}

extern "C" void kernel_launch(void* const* d_in, const int* in_sizes, int n_in,
                              void* d_out, int out_size, void* d_ws, size_t ws_size,
                              hipStream_t stream) {
    const float* feat  = (const float*)d_in[0];
    const int*   coors = (const int*)d_in[1];
    const float* W     = (const float*)d_in[3];
    float*       out   = (float*)d_out;

    const int N = in_sizes[0] / CIN;  // 200000

    char* ws = (char*)d_ws;
    int* map = (int*)ws;                                        // 7,077,888 B
    int* nxt = (int*)(ws + (size_t)NSITE * 4);                  //   800,000 B
    const size_t featbf_off = (size_t)NSITE * 4 + (((size_t)N * 4 + 63) & ~(size_t)63);
    unsigned short* featbf = (unsigned short*)(ws + featbf_off);        // 12.8 MB
    const size_t wpack_off = featbf_off + (((size_t)N * CIN * 2 + 15) & ~(size_t)15);
    unsigned short* Wpack = (unsigned short*)(ws + wpack_off);          // 110,592 B
    // total ws use ~20.8 MB

    const int prep_blocks = (NSITE / 4 + WPACK_ELEMS + 255) / 256;
    prep_kernel<<<prep_blocks, 256, 0, stream>>>(W, map, Wpack);

    build_map_kernel<<<(N + 255) / 256, 256, 0, stream>>>(coors, map, nxt, N);

    merge_feat_kernel<<<(N * 8 + 255) / 256, 256, 0, stream>>>(
        feat, coors, map, nxt, featbf, N);

    spconv_gather_kernel<<<NWAVE / 4, 256, 0, stream>>>(featbf, map, Wpack, out);
}